// Round 3
// baseline (993.141 us; speedup 1.0000x reference)
//
#include <hip/hip_runtime.h>
#include <hip/hip_bf16.h>
#include <stdint.h>
#include <string.h>

// ---------------------------------------------------------------------------
// Mamba2 block: x@w_in^T -> split(xi,gate) -> depthwise causal conv4 + silu
//               -> *D*silu(gate) -> @w_out^T
// B=4, T=2048, D_MODEL=2048, D_INNER=4096.  GEMMs in bf16 MFMA, fp32 acc.
//
// R6: 256^2 / BK=64 / 8-wave / 8-phase schedule, vmcnt(6) publishes at
//     phases 4/8.  Measured 1072 TF, MfmaUtil 50% — the 2-barrier-per-phase
//     lockstep serializes the LDS-read window against the MFMA window
//     (512 cyc MFMA vs ~600 cyc LDS per phase per CU, alternating).
// R7: single barrier per region; each region's ds_reads moved into the
//     PREVIOUS region so reads+MFMA co-reside between barriers and the
//     compiler's native counted lgkmcnt interleaves them (LDS issue hides
//     under MFMA issue).  Read-early audit:
//       - b1 (B q1,q3 of cur buf) issued in R1, consumed by R2's MFMA ->
//         lgkm-complete before R2-end BAR; overwriting stages are R3/R5 —
//         both >= 1 barrier after the consumer.  R1's own stage targets the
//         OTHER buffer.
//       - a1 (A q1,q3) issued in R2, consumed R3/R4; stage of those rows is
//         R4 (after R3-end BAR).  R2's stage writes A q0,q2 — disjoint.
//       - R5/R1 cold reads stay in their own region (must not cross the
//         vmcnt publish; VM6's "memory" clobber pins them).
//     Stage order and VM6 points identical to the verified R6 kernel.
// R8: resubmission of R7 — round 2 died to container/infra failure with no
//     kernel-level signal (no pass/fail, no counters).  Audit re-verified:
//     no new addresses vs R6, uniform barrier counts, same vmcnt invariants.
// ---------------------------------------------------------------------------

#define BT_TOTAL 8192   // B*T
#define DM 2048
#define DI 4096

typedef __attribute__((ext_vector_type(8)))  short short8;   // 8 x bf16
typedef __attribute__((ext_vector_type(16))) float f32x16;   // 32x32 C/D

__device__ __forceinline__ void async_ld16(const void* g, void* l) {
    __builtin_amdgcn_global_load_lds(
        (__attribute__((address_space(1))) void*)g,
        (__attribute__((address_space(3))) void*)l,
        16, 0, 0);
}

__device__ __forceinline__ float bf2f(ushort u) {
    union { uint i; float f; } v; v.i = ((uint)u) << 16; return v.f;
}

__device__ __forceinline__ ushort f2bf_bits(float f) {
    union { __hip_bfloat16 b; ushort u; } v;
    v.b = __float2bfloat16(f);
    return v.u;
}

// LDS regions (ushort indices), 128 KiB total: [A buf0][B buf0][A buf1][B buf1]
#define RA0 0
#define RB0 16384
#define RA1 32768
#define RB1 49152

#define BAR()   asm volatile("s_barrier" ::: "memory")
#define VM6()   asm volatile("s_waitcnt vmcnt(6)" ::: "memory")
#define VM0()   asm volatile("s_waitcnt vmcnt(0)" ::: "memory")
#define PRIO1() __builtin_amdgcn_s_setprio(1)
#define PRIO0() __builtin_amdgcn_s_setprio(0)

// gemm256: C[M,N] = A[M,K] * B[N,K]^T (both K-contiguous), bf16 in, fp32 acc.
// Requires M%256==0, N%256==0, K%128==0, K>=256, grid=(N/256, M/256), 512 thr.
template<bool OUT_BF16>
__global__ __launch_bounds__(512, 2) void gemm256_kernel(
    const ushort* __restrict__ A, const ushort* __restrict__ B,
    void* __restrict__ Cp, int M, int N, int K)
{
    __shared__ ushort lds[65536];   // 128 KiB

    const int tid  = threadIdx.x;
    const int lane = tid & 63;
    const int wave = tid >> 6;      // 8 waves: 2 (M) x 4 (N)
    const int wm   = wave >> 2;     // 0..1 -> 128 rows each
    const int wn   = wave & 3;      // 0..3 -> 64 cols each
    const int l31  = lane & 31;
    const int half = lane >> 5;

    // XCD-aware bijective block swizzle (nwg % 8 == 0 for all our launches)
    const int nbx = gridDim.x;
    const int nwg = nbx * gridDim.y;
    int orig = blockIdx.y * nbx + blockIdx.x;
    orig = (orig & 7) * (nwg >> 3) + (orig >> 3);
    const int bn = (orig % nbx) * 256;
    const int bm = (orig / nbx) * 256;

    // ---- staging precompute: thread tid covers 16B chunk (tid) of a
    //      64-row x 64-col quarter; source chunk pre-swizzled by f(row).
    const int rq = tid >> 3;                 // row within quarter
    const int jq = tid & 7;                  // chunk within row
    const int fq = (rq ^ (rq >> 3)) & 7;     // == f(qrow + rq) for qrow%64==0
    const int goffA = (bm + rq) * K + ((jq ^ fq) * 8);
    const int goffB = (bn + rq) * K + ((jq ^ fq) * 8);
    const int dst8  = tid * 8;               // linear LDS dest (ushorts)

    // ---- reader precompute (32x32x16 frags; logical chunk q = ks*2 + half,
    //      physical chunk = q ^ ((frag&1)*4) ^ flane)
    const int flane = (l31 ^ (l31 >> 3)) & 7;
    const int cl8   = (half ^ flane) * 8;            // chunk-xor base, x8 ush
    const int aBase = (wm * 128 + l31) * 64;         // within A region
    const int bBase = (wn * 64  + l31) * 64;         // within B region

    f32x16 acc[4][2];
#pragma unroll
    for (int m = 0; m < 4; ++m)
#pragma unroll
        for (int n = 0; n < 2; ++n)
#pragma unroll
            for (int r = 0; r < 16; ++r)
                acc[m][n][r] = 0.f;

    short8 a0E[4], a0O[4], a1E[4], a1O[4], b0[4], b1[4];

#define STA(P, QROW, REG) async_ld16((P) + (size_t)(QROW) * K + goffA, \
                                     &lds[(REG) + (QROW) * 64 + dst8])
#define STB(P, QROW, REG) async_ld16((P) + (size_t)(QROW) * K + goffB, \
                                     &lds[(REG) + (QROW) * 64 + dst8])

#define RDA(DE, DO, MH, REG) do { \
    _Pragma("unroll") \
    for (int ks = 0; ks < 4; ++ks) { \
        DE[ks] = *(const short8*)&lds[(REG) + aBase + (MH)*4096 + (cl8 ^ (ks<<4))]; \
        DO[ks] = *(const short8*)&lds[(REG) + aBase + (MH)*4096 + 2048 + (cl8 ^ (ks<<4) ^ 32)]; \
    } } while (0)

#define RDB(DSTV, NF, REG) do { \
    _Pragma("unroll") \
    for (int ks = 0; ks < 4; ++ks) { \
        DSTV[ks] = *(const short8*)&lds[(REG) + bBase + (NF)*2048 + (cl8 ^ (ks<<4) ^ ((NF)<<5))]; \
    } } while (0)

#define MMA(MH, NH, AE, AO, BF) do { \
    _Pragma("unroll") \
    for (int ks = 0; ks < 4; ++ks) { \
        acc[(MH)*2    ][(NH)] = __builtin_amdgcn_mfma_f32_32x32x16_bf16( \
            AE[ks], BF[ks], acc[(MH)*2    ][(NH)], 0, 0, 0); \
        acc[(MH)*2 + 1][(NH)] = __builtin_amdgcn_mfma_f32_32x32x16_bf16( \
            AO[ks], BF[ks], acc[(MH)*2 + 1][(NH)], 0, 0, 0); \
    } } while (0)

    // ---- prologue: tile0 (8 quarters) + tile1 (6 quarters); the 7th/8th
    //      quarters of tile1 (B q1,q3) are staged in R1 of iter 0.
    {
        STA(A, 0, RA0);  STA(A, 128, RA0);
        STB(B, 0, RB0);  STB(B, 128, RB0);
        STA(A, 64, RA0); STA(A, 192, RA0);
        STB(B, 64, RB0); STB(B, 192, RB0);
        const ushort* Ap = A + 64;
        const ushort* Bp = B + 64;
        STA(Ap, 0, RA1);  STA(Ap, 128, RA1);
        STB(Bp, 0, RB1);  STB(Bp, 128, RB1);
        STA(Ap, 64, RA1); STA(Ap, 192, RA1);
        VM6(); BAR();   // tile0's 8 loads landed; tile1's 6 still in flight
    }

    const int NITER = K >> 7;   // 2 K-tiles (2x64) per iteration
    for (int i = 0; i < NITER; ++i) {
        const bool last = (i == NITER - 1);
        const int k1 = 128 * i + 64;    // K-tile 2i+1
        const int k2 = 128 * i + 128;   // K-tile 2i+2
        const int k3 = 128 * i + 192;   // K-tile 2i+3

        // R1: reads for Q00 + Q01 (buf0) | stage B(k1) q1,q3 -> buf1 | Q00
        RDA(a0E, a0O, 0, RA0);
        RDB(b0, 0, RB0);
        RDB(b1, 1, RB0);
        STB(B + k1, 64, RB1); STB(B + k1, 192, RB1);
        PRIO1(); MMA(0, 0, a0E, a0O, b0); PRIO0();
        BAR();

        // R2: read a1 (A q1,q3 buf0) | stage A(k2) q0,q2 -> buf0 | Q01
        RDA(a1E, a1O, 1, RA0);
        if (!last) { STA(A + k2, 0, RA0); STA(A + k2, 128, RA0); }
        PRIO1(); MMA(0, 1, a0E, a0O, b1); PRIO0();
        BAR();

        // R3: stage B(k2) q0,q2 -> buf0 | Q11
        if (!last) { STB(B + k2, 0, RB0); STB(B + k2, 128, RB0); }
        PRIO1(); MMA(1, 1, a1E, a1O, b1); PRIO0();
        BAR();

        // R4: stage A(k2) q1,q3 -> buf0 | Q10 | publish buf1 (tile 2i+1)
        if (!last) { STA(A + k2, 64, RA0); STA(A + k2, 192, RA0); }
        PRIO1(); MMA(1, 0, a1E, a1O, b0); PRIO0();
        if (last) { VM0(); } else { VM6(); }
        BAR();

        // R5: reads for Q00 + Q01 (buf1) | stage B(k2) q1,q3 -> buf0 | Q00
        RDA(a0E, a0O, 0, RA1);
        RDB(b0, 0, RB1);
        RDB(b1, 1, RB1);
        if (!last) { STB(B + k2, 64, RB0); STB(B + k2, 192, RB0); }
        PRIO1(); MMA(0, 0, a0E, a0O, b0); PRIO0();
        BAR();

        // R6: read a1 (A q1,q3 buf1) | stage A(k3) q0,q2 -> buf1 | Q01
        RDA(a1E, a1O, 1, RA1);
        if (!last) { STA(A + k3, 0, RA1); STA(A + k3, 128, RA1); }
        PRIO1(); MMA(0, 1, a0E, a0O, b1); PRIO0();
        BAR();

        // R7: stage B(k3) q0,q2 -> buf1 | Q11
        if (!last) { STB(B + k3, 0, RB1); STB(B + k3, 128, RB1); }
        PRIO1(); MMA(1, 1, a1E, a1O, b1); PRIO0();
        BAR();

        // R8: stage A(k3) q1,q3 -> buf1 | Q10 | publish buf0 (tile 2i+2)
        if (!last) { STA(A + k3, 64, RA1); STA(A + k3, 192, RA1); }
        PRIO1(); MMA(1, 0, a1E, a1O, b0); PRIO0();
        if (!last) { VM6(); BAR(); }
    }

    // ---- epilogue. 32x32 C/D layout (verified m74/m101):
    //   col = lane&31, row = (reg&3) + 8*(reg>>2) + 4*(lane>>5)
    const int col0 = bn + wn * 64 + l31;
    const int row0 = bm + wm * 128 + 4 * half;
    if (OUT_BF16) {
        __hip_bfloat16* C = (__hip_bfloat16*)Cp;
#pragma unroll
        for (int m = 0; m < 4; ++m)
#pragma unroll
            for (int n = 0; n < 2; ++n)
#pragma unroll
                for (int r = 0; r < 16; ++r) {
                    const int row = row0 + m * 32 + (r & 3) + 8 * (r >> 2);
                    C[(size_t)row * (size_t)N + col0 + n * 32] =
                        __float2bfloat16(acc[m][n][r]);
                }
    } else {
        float* C = (float*)Cp;
#pragma unroll
        for (int m = 0; m < 4; ++m)
#pragma unroll
            for (int n = 0; n < 2; ++n)
#pragma unroll
                for (int r = 0; r < 16; ++r) {
                    const int row = row0 + m * 32 + (r & 3) + 8 * (r >> 2);
                    C[(size_t)row * (size_t)N + col0 + n * 32] = acc[m][n][r];
                }
    }
}

// Depthwise causal conv (4 taps) + silu, * D, * silu(gate).  8 d's / thread.
__global__ __launch_bounds__(256) void conv_silu_kernel(
    const ushort* __restrict__ xp,   // bf16 [8192][8192]
    const float* __restrict__ cw,    // [4096][4]
    const float* __restrict__ cb,    // [4096]
    const float* __restrict__ Dv,    // [4096]
    ushort* __restrict__ h)          // bf16 [8192][4096]
{
    const int v  = blockIdx.x * 256 + threadIdx.x;   // over 8192*512
    const int d8 = (v & 511) * 8;
    const int bt = v >> 9;
    const int t  = bt & 2047;

    const uint4 gv = *(const uint4*)(xp + (size_t)bt * (2 * DI) + DI + d8);
    uint4 tap[4];
#pragma unroll
    for (int k = 0; k < 4; ++k) {
        const int tt = t - 3 + k;
        if (tt >= 0)
            tap[k] = *(const uint4*)(xp + (size_t)(bt - 3 + k) * (2 * DI) + d8);
        else
            tap[k] = (uint4){0u, 0u, 0u, 0u};
    }

    const float4* cwv = (const float4*)(cw + (size_t)d8 * 4);   // 8 x float4
    const float4  cb0 = *(const float4*)(cb + d8);
    const float4  cb1 = *(const float4*)(cb + d8 + 4);
    const float4  dv0 = *(const float4*)(Dv + d8);
    const float4  dv1 = *(const float4*)(Dv + d8 + 4);
    const float cbs[8] = {cb0.x, cb0.y, cb0.z, cb0.w, cb1.x, cb1.y, cb1.z, cb1.w};
    const float dvs[8] = {dv0.x, dv0.y, dv0.z, dv0.w, dv1.x, dv1.y, dv1.z, dv1.w};

    ushort res[8];
#pragma unroll
    for (int j = 0; j < 8; ++j) {
        float a = cbs[j];
        const float4 w = cwv[j];
        const float wk[4] = {w.x, w.y, w.z, w.w};
#pragma unroll
        for (int k = 0; k < 4; ++k) {
            const uint u = ((const uint*)&tap[k])[j >> 1];
            const ushort us = (j & 1) ? (ushort)(u >> 16) : (ushort)(u & 0xffff);
            a += bf2f(us) * wk[k];
        }
        const uint gu = ((const uint*)&gv)[j >> 1];
        const ushort gs = (j & 1) ? (ushort)(gu >> 16) : (ushort)(gu & 0xffff);
        const float g = bf2f(gs);
        const float sc = a / (1.f + __expf(-a));
        const float sg = g / (1.f + __expf(-g));
        res[j] = f2bf_bits(sc * dvs[j] * sg);
    }
    *(uint4*)(h + (size_t)bt * DI + d8) = *(const uint4*)res;
}

__global__ __launch_bounds__(256) void f32_to_bf16_x4(
    const float* __restrict__ in, __hip_bfloat16* __restrict__ out, int n4)
{
    const int i = blockIdx.x * 256 + threadIdx.x;
    if (i >= n4) return;
    const float4 v = *(const float4*)(in + (size_t)i * 4);
    union { __hip_bfloat16 hh[4]; ushort4 u; } cv;
    cv.hh[0] = __float2bfloat16(v.x);
    cv.hh[1] = __float2bfloat16(v.y);
    cv.hh[2] = __float2bfloat16(v.z);
    cv.hh[3] = __float2bfloat16(v.w);
    *(ushort4*)((ushort*)out + (size_t)i * 4) = cv.u;
}

extern "C" void kernel_launch(void* const* d_in, const int* in_sizes, int n_in,
                              void* d_out, int out_size, void* d_ws, size_t ws_size,
                              hipStream_t stream)
{
    const float* x     = (const float*)d_in[0];   // [4,2048,2048]
    const float* w_in  = (const float*)d_in[1];   // [8192,2048]
    const float* w_out = (const float*)d_in[2];   // [2048,4096]
    const float* cw    = (const float*)d_in[3];   // [4096,1,4]
    const float* cb    = (const float*)d_in[4];   // [4096]
    const float* Dv    = (const float*)d_in[5];   // [4096]
    float* out = (float*)d_out;                   // [4,2048,2048]

    // Workspace layout (208 MiB):
    //   [0, 128M)        x_proj bf16 [8192][8192]
    //   [128M, 192M)     phase 1: xb (32M) + winb (32M); phase 2: h bf16 (64M)
    //   [192M, 208M)     woutb [2048][4096] bf16
    char* wsc = (char*)d_ws;
    __hip_bfloat16* xproj = (__hip_bfloat16*)wsc;
    __hip_bfloat16* xb    = (__hip_bfloat16*)(wsc + (size_t)134217728);
    __hip_bfloat16* winb  = (__hip_bfloat16*)(wsc + (size_t)134217728 + 33554432);
    __hip_bfloat16* hbuf  = (__hip_bfloat16*)(wsc + (size_t)134217728);  // aliases xb/winb
    __hip_bfloat16* woutb = (__hip_bfloat16*)(wsc + (size_t)201326592);

    // 1) fp32 -> bf16 converts
    f32_to_bf16_x4<<<(BT_TOTAL * DM / 4 + 255) / 256, 256, 0, stream>>>(x, xb, BT_TOTAL * DM / 4);
    f32_to_bf16_x4<<<(2 * DI * DM / 4 + 255) / 256, 256, 0, stream>>>(w_in, winb, 2 * DI * DM / 4);
    f32_to_bf16_x4<<<(DM * DI / 4 + 255) / 256, 256, 0, stream>>>(w_out, woutb, DM * DI / 4);

    // 2) GEMM1: x_proj[bt,d] = sum_c x[bt,c] * w_in[d,c]   (M=8192,N=8192,K=2048)
    gemm256_kernel<true><<<dim3((2 * DI) / 256, BT_TOTAL / 256), 512, 0, stream>>>(
        (const ushort*)xb, (const ushort*)winb, xproj, BT_TOTAL, 2 * DI, DM);

    // 3) conv + silu + gate  (writes hbuf over dead xb/winb — stream-ordered)
    conv_silu_kernel<<<(BT_TOTAL * DI / 8) / 256, 256, 0, stream>>>(
        (const ushort*)xproj, cw, cb, Dv, (ushort*)hbuf);

    // 4) GEMM2: out[bt,c] = sum_d h[bt,d] * w_out[c,d]   (M=8192,N=2048,K=4096)
    gemm256_kernel<false><<<dim3(DM / 256, BT_TOTAL / 256), 512, 0, stream>>>(
        (const ushort*)hbuf, (const ushort*)woutb, out, BT_TOTAL, DM, DI);
}

// Round 4
// 647.062 us; speedup vs baseline: 1.5348x; 1.5348x over previous
//
#include <hip/hip_runtime.h>
#include <hip/hip_bf16.h>
#include <stdint.h>
#include <string.h>

// ---------------------------------------------------------------------------
// Mamba2 block: x@w_in^T -> split(xi,gate) -> depthwise causal conv4 + silu
//               -> *D*silu(gate) -> @w_out^T
// B=4, T=2048, D_MODEL=2048, D_INNER=4096.  GEMMs in bf16 MFMA, fp32 acc.
//
// R6: 256^2 / BK=64 / 8-wave / 8-phase schedule, vmcnt(6) publishes at
//     phases 4/8.  1072 TF, MfmaUtil 50% — mid-phase {BAR;LGKM0} forces all
//     waves to drain the LDS-read window before ANY enters the MFMA window:
//     the LDS pipe (~600 cyc/phase) and MFMA pipe (512 cyc/phase) alternate
//     instead of overlapping.
// R7/R8: read-early + A-frag double-buffer -> +32 VGPR -> past the 256 cap
//     (launch_bounds 512,2) -> scratch spills in the K-loop.  Counters:
//     WRITE_SIZE 147->272 MB (only scratch can add writes), FETCH +190 MB,
//     MfmaUtil 21%.  Discarded.
// R9: single barrier per phase with R6's EXACT read placement and register
//     set (aE/aO reused across halves, b0, b1 — no extra frags).  Safety:
//     every ds_read is consumed by an MFMA in its own phase, so it is
//     lgkm-retired before that wave's end-of-phase barrier; a stage in
//     phase p targets rows last read in phase <= p-1, separated by that
//     barrier.  Removing the mid-phase BAR lets waves slip within a phase:
//     one wave's LDS-read window overlaps another's MFMA window (separate
//     pipes).  Stage order + VM6/VM0 publish points verbatim R6.
// ---------------------------------------------------------------------------

#define BT_TOTAL 8192   // B*T
#define DM 2048
#define DI 4096

typedef __attribute__((ext_vector_type(8)))  short short8;   // 8 x bf16
typedef __attribute__((ext_vector_type(16))) float f32x16;   // 32x32 C/D

__device__ __forceinline__ void async_ld16(const void* g, void* l) {
    __builtin_amdgcn_global_load_lds(
        (__attribute__((address_space(1))) void*)g,
        (__attribute__((address_space(3))) void*)l,
        16, 0, 0);
}

__device__ __forceinline__ float bf2f(ushort u) {
    union { uint i; float f; } v; v.i = ((uint)u) << 16; return v.f;
}

__device__ __forceinline__ ushort f2bf_bits(float f) {
    union { __hip_bfloat16 b; ushort u; } v;
    v.b = __float2bfloat16(f);
    return v.u;
}

// LDS regions (ushort indices), 128 KiB total: [A buf0][B buf0][A buf1][B buf1]
#define RA0 0
#define RB0 16384
#define RA1 32768
#define RB1 49152

#define BAR()   asm volatile("s_barrier" ::: "memory")
#define VM6()   asm volatile("s_waitcnt vmcnt(6)" ::: "memory")
#define VM0()   asm volatile("s_waitcnt vmcnt(0)" ::: "memory")
#define PRIO1() __builtin_amdgcn_s_setprio(1)
#define PRIO0() __builtin_amdgcn_s_setprio(0)

// gemm256: C[M,N] = A[M,K] * B[N,K]^T (both K-contiguous), bf16 in, fp32 acc.
// Requires M%256==0, N%256==0, K%128==0, K>=256, grid=(N/256, M/256), 512 thr.
template<bool OUT_BF16>
__global__ __launch_bounds__(512, 2) void gemm256_kernel(
    const ushort* __restrict__ A, const ushort* __restrict__ B,
    void* __restrict__ Cp, int M, int N, int K)
{
    __shared__ ushort lds[65536];   // 128 KiB

    const int tid  = threadIdx.x;
    const int lane = tid & 63;
    const int wave = tid >> 6;      // 8 waves: 2 (M) x 4 (N)
    const int wm   = wave >> 2;     // 0..1 -> 128 rows each
    const int wn   = wave & 3;      // 0..3 -> 64 cols each
    const int l31  = lane & 31;
    const int half = lane >> 5;

    // XCD-aware bijective block swizzle (nwg % 8 == 0 for all our launches)
    const int nbx = gridDim.x;
    const int nwg = nbx * gridDim.y;
    int orig = blockIdx.y * nbx + blockIdx.x;
    orig = (orig & 7) * (nwg >> 3) + (orig >> 3);
    const int bn = (orig % nbx) * 256;
    const int bm = (orig / nbx) * 256;

    // ---- staging precompute: thread tid covers 16B chunk (tid) of a
    //      64-row x 64-col quarter; source chunk pre-swizzled by f(row).
    const int rq = tid >> 3;                 // row within quarter
    const int jq = tid & 7;                  // chunk within row
    const int fq = (rq ^ (rq >> 3)) & 7;     // == f(qrow + rq) for qrow%64==0
    const int goffA = (bm + rq) * K + ((jq ^ fq) * 8);
    const int goffB = (bn + rq) * K + ((jq ^ fq) * 8);
    const int dst8  = tid * 8;               // linear LDS dest (ushorts)

    // ---- reader precompute (32x32x16 frags; logical chunk q = ks*2 + half,
    //      physical chunk = q ^ ((frag&1)*4) ^ flane)
    const int flane = (l31 ^ (l31 >> 3)) & 7;
    const int cl8   = (half ^ flane) * 8;            // chunk-xor base, x8 ush
    const int aBase = (wm * 128 + l31) * 64;         // within A region
    const int bBase = (wn * 64  + l31) * 64;         // within B region

    f32x16 acc[4][2];
#pragma unroll
    for (int m = 0; m < 4; ++m)
#pragma unroll
        for (int n = 0; n < 2; ++n)
#pragma unroll
            for (int r = 0; r < 16; ++r)
                acc[m][n][r] = 0.f;

    short8 aE[4], aO[4], b0[4], b1[4];   // R6 register set — no spill

#define STA(P, QROW, REG) async_ld16((P) + (size_t)(QROW) * K + goffA, \
                                     &lds[(REG) + (QROW) * 64 + dst8])
#define STB(P, QROW, REG) async_ld16((P) + (size_t)(QROW) * K + goffB, \
                                     &lds[(REG) + (QROW) * 64 + dst8])

#define RDA(MH, REG) do { \
    _Pragma("unroll") \
    for (int ks = 0; ks < 4; ++ks) { \
        aE[ks] = *(const short8*)&lds[(REG) + aBase + (MH)*4096 + (cl8 ^ (ks<<4))]; \
        aO[ks] = *(const short8*)&lds[(REG) + aBase + (MH)*4096 + 2048 + (cl8 ^ (ks<<4) ^ 32)]; \
    } } while (0)

#define RDB(DSTV, NF, REG) do { \
    _Pragma("unroll") \
    for (int ks = 0; ks < 4; ++ks) { \
        DSTV[ks] = *(const short8*)&lds[(REG) + bBase + (NF)*2048 + (cl8 ^ (ks<<4) ^ ((NF)<<5))]; \
    } } while (0)

#define MMA(MH, NH, BF) do { \
    _Pragma("unroll") \
    for (int ks = 0; ks < 4; ++ks) { \
        acc[(MH)*2    ][(NH)] = __builtin_amdgcn_mfma_f32_32x32x16_bf16( \
            aE[ks], BF[ks], acc[(MH)*2    ][(NH)], 0, 0, 0); \
        acc[(MH)*2 + 1][(NH)] = __builtin_amdgcn_mfma_f32_32x32x16_bf16( \
            aO[ks], BF[ks], acc[(MH)*2 + 1][(NH)], 0, 0, 0); \
    } } while (0)

    // ---- prologue: tile0 (8 quarters) + tile1 (6 quarters); the 7th/8th
    //      quarters of tile1 (B q1,q3) are staged in phase 1 of iter 0.
    {
        STA(A, 0, RA0);  STA(A, 128, RA0);
        STB(B, 0, RB0);  STB(B, 128, RB0);
        STA(A, 64, RA0); STA(A, 192, RA0);
        STB(B, 64, RB0); STB(B, 192, RB0);
        const ushort* Ap = A + 64;
        const ushort* Bp = B + 64;
        STA(Ap, 0, RA1);  STA(Ap, 128, RA1);
        STB(Bp, 0, RB1);  STB(Bp, 128, RB1);
        STA(Ap, 64, RA1); STA(Ap, 192, RA1);
        VM6(); BAR();   // tile0's 8 loads landed; tile1's 6 still in flight
    }

    const int NITER = K >> 7;   // 2 K-tiles (2x64) per iteration
    for (int i = 0; i < NITER; ++i) {
        const bool last = (i == NITER - 1);
        const int k1 = 128 * i + 64;    // K-tile 2i+1
        const int k2 = 128 * i + 128;   // K-tile 2i+2
        const int k3 = 128 * i + 192;   // K-tile 2i+3

        // phase 1: reads a(MH0)+b0 (buf0) | stage B(k1) q1,q3 -> buf1 | Q00
        RDA(0, RA0); RDB(b0, 0, RB0);
        STB(B + k1, 64, RB1); STB(B + k1, 192, RB1);
        PRIO1(); MMA(0, 0, b0); PRIO0();
        BAR();

        // phase 2: read b1 (buf0) | stage A(k2) q0,q2 -> buf0 | Q01
        RDB(b1, 1, RB0);
        if (!last) { STA(A + k2, 0, RA0); STA(A + k2, 128, RA0); }
        PRIO1(); MMA(0, 1, b1); PRIO0();
        BAR();

        // phase 3: read a(MH1) (buf0) | stage B(k2) q0,q2 -> buf0 | Q11
        RDA(1, RA0);
        if (!last) { STB(B + k2, 0, RB0); STB(B + k2, 128, RB0); }
        PRIO1(); MMA(1, 1, b1); PRIO0();
        BAR();

        // phase 4: stage A(k2) q1,q3 -> buf0 | Q10 | publish buf1 (tile 2i+1)
        if (!last) { STA(A + k2, 64, RA0); STA(A + k2, 192, RA0); }
        PRIO1(); MMA(1, 0, b0); PRIO0();
        if (last) { VM0(); } else { VM6(); }
        BAR();

        // phase 5: reads a(MH0)+b0 (buf1) | stage B(k2) q1,q3 -> buf0 | Q00
        RDA(0, RA1); RDB(b0, 0, RB1);
        if (!last) { STB(B + k2, 64, RB0); STB(B + k2, 192, RB0); }
        PRIO1(); MMA(0, 0, b0); PRIO0();
        BAR();

        // phase 6: read b1 (buf1) | stage A(k3) q0,q2 -> buf1 | Q01
        RDB(b1, 1, RB1);
        if (!last) { STA(A + k3, 0, RA1); STA(A + k3, 128, RA1); }
        PRIO1(); MMA(0, 1, b1); PRIO0();
        BAR();

        // phase 7: read a(MH1) (buf1) | stage B(k3) q0,q2 -> buf1 | Q11
        RDA(1, RA1);
        if (!last) { STB(B + k3, 0, RB1); STB(B + k3, 128, RB1); }
        PRIO1(); MMA(1, 1, b1); PRIO0();
        BAR();

        // phase 8: stage A(k3) q1,q3 -> buf1 | Q10 | publish buf0 (tile 2i+2)
        if (!last) { STA(A + k3, 64, RA1); STA(A + k3, 192, RA1); }
        PRIO1(); MMA(1, 0, b0); PRIO0();
        if (!last) { VM6(); BAR(); }
    }

    // ---- epilogue. 32x32 C/D layout (verified m74/m101):
    //   col = lane&31, row = (reg&3) + 8*(reg>>2) + 4*(lane>>5)
    const int col0 = bn + wn * 64 + l31;
    const int row0 = bm + wm * 128 + 4 * half;
    if (OUT_BF16) {
        __hip_bfloat16* C = (__hip_bfloat16*)Cp;
#pragma unroll
        for (int m = 0; m < 4; ++m)
#pragma unroll
            for (int n = 0; n < 2; ++n)
#pragma unroll
                for (int r = 0; r < 16; ++r) {
                    const int row = row0 + m * 32 + (r & 3) + 8 * (r >> 2);
                    C[(size_t)row * (size_t)N + col0 + n * 32] =
                        __float2bfloat16(acc[m][n][r]);
                }
    } else {
        float* C = (float*)Cp;
#pragma unroll
        for (int m = 0; m < 4; ++m)
#pragma unroll
            for (int n = 0; n < 2; ++n)
#pragma unroll
                for (int r = 0; r < 16; ++r) {
                    const int row = row0 + m * 32 + (r & 3) + 8 * (r >> 2);
                    C[(size_t)row * (size_t)N + col0 + n * 32] = acc[m][n][r];
                }
    }
}

// Depthwise causal conv (4 taps) + silu, * D, * silu(gate).  8 d's / thread.
__global__ __launch_bounds__(256) void conv_silu_kernel(
    const ushort* __restrict__ xp,   // bf16 [8192][8192]
    const float* __restrict__ cw,    // [4096][4]
    const float* __restrict__ cb,    // [4096]
    const float* __restrict__ Dv,    // [4096]
    ushort* __restrict__ h)          // bf16 [8192][4096]
{
    const int v  = blockIdx.x * 256 + threadIdx.x;   // over 8192*512
    const int d8 = (v & 511) * 8;
    const int bt = v >> 9;
    const int t  = bt & 2047;

    const uint4 gv = *(const uint4*)(xp + (size_t)bt * (2 * DI) + DI + d8);
    uint4 tap[4];
#pragma unroll
    for (int k = 0; k < 4; ++k) {
        const int tt = t - 3 + k;
        if (tt >= 0)
            tap[k] = *(const uint4*)(xp + (size_t)(bt - 3 + k) * (2 * DI) + d8);
        else
            tap[k] = (uint4){0u, 0u, 0u, 0u};
    }

    const float4* cwv = (const float4*)(cw + (size_t)d8 * 4);   // 8 x float4
    const float4  cb0 = *(const float4*)(cb + d8);
    const float4  cb1 = *(const float4*)(cb + d8 + 4);
    const float4  dv0 = *(const float4*)(Dv + d8);
    const float4  dv1 = *(const float4*)(Dv + d8 + 4);
    const float cbs[8] = {cb0.x, cb0.y, cb0.z, cb0.w, cb1.x, cb1.y, cb1.z, cb1.w};
    const float dvs[8] = {dv0.x, dv0.y, dv0.z, dv0.w, dv1.x, dv1.y, dv1.z, dv1.w};

    ushort res[8];
#pragma unroll
    for (int j = 0; j < 8; ++j) {
        float a = cbs[j];
        const float4 w = cwv[j];
        const float wk[4] = {w.x, w.y, w.z, w.w};
#pragma unroll
        for (int k = 0; k < 4; ++k) {
            const uint u = ((const uint*)&tap[k])[j >> 1];
            const ushort us = (j & 1) ? (ushort)(u >> 16) : (ushort)(u & 0xffff);
            a += bf2f(us) * wk[k];
        }
        const uint gu = ((const uint*)&gv)[j >> 1];
        const ushort gs = (j & 1) ? (ushort)(gu >> 16) : (ushort)(gu & 0xffff);
        const float g = bf2f(gs);
        const float sc = a / (1.f + __expf(-a));
        const float sg = g / (1.f + __expf(-g));
        res[j] = f2bf_bits(sc * dvs[j] * sg);
    }
    *(uint4*)(h + (size_t)bt * DI + d8) = *(const uint4*)res;
}

__global__ __launch_bounds__(256) void f32_to_bf16_x4(
    const float* __restrict__ in, __hip_bfloat16* __restrict__ out, int n4)
{
    const int i = blockIdx.x * 256 + threadIdx.x;
    if (i >= n4) return;
    const float4 v = *(const float4*)(in + (size_t)i * 4);
    union { __hip_bfloat16 hh[4]; ushort4 u; } cv;
    cv.hh[0] = __float2bfloat16(v.x);
    cv.hh[1] = __float2bfloat16(v.y);
    cv.hh[2] = __float2bfloat16(v.z);
    cv.hh[3] = __float2bfloat16(v.w);
    *(ushort4*)((ushort*)out + (size_t)i * 4) = cv.u;
}

extern "C" void kernel_launch(void* const* d_in, const int* in_sizes, int n_in,
                              void* d_out, int out_size, void* d_ws, size_t ws_size,
                              hipStream_t stream)
{
    const float* x     = (const float*)d_in[0];   // [4,2048,2048]
    const float* w_in  = (const float*)d_in[1];   // [8192,2048]
    const float* w_out = (const float*)d_in[2];   // [2048,4096]
    const float* cw    = (const float*)d_in[3];   // [4096,1,4]
    const float* cb    = (const float*)d_in[4];   // [4096]
    const float* Dv    = (const float*)d_in[5];   // [4096]
    float* out = (float*)d_out;                   // [4,2048,2048]

    // Workspace layout (208 MiB):
    //   [0, 128M)        x_proj bf16 [8192][8192]
    //   [128M, 192M)     phase 1: xb (32M) + winb (32M); phase 2: h bf16 (64M)
    //   [192M, 208M)     woutb [2048][4096] bf16
    char* wsc = (char*)d_ws;
    __hip_bfloat16* xproj = (__hip_bfloat16*)wsc;
    __hip_bfloat16* xb    = (__hip_bfloat16*)(wsc + (size_t)134217728);
    __hip_bfloat16* winb  = (__hip_bfloat16*)(wsc + (size_t)134217728 + 33554432);
    __hip_bfloat16* hbuf  = (__hip_bfloat16*)(wsc + (size_t)134217728);  // aliases xb/winb
    __hip_bfloat16* woutb = (__hip_bfloat16*)(wsc + (size_t)201326592);

    // 1) fp32 -> bf16 converts
    f32_to_bf16_x4<<<(BT_TOTAL * DM / 4 + 255) / 256, 256, 0, stream>>>(x, xb, BT_TOTAL * DM / 4);
    f32_to_bf16_x4<<<(2 * DI * DM / 4 + 255) / 256, 256, 0, stream>>>(w_in, winb, 2 * DI * DM / 4);
    f32_to_bf16_x4<<<(DM * DI / 4 + 255) / 256, 256, 0, stream>>>(w_out, woutb, DM * DI / 4);

    // 2) GEMM1: x_proj[bt,d] = sum_c x[bt,c] * w_in[d,c]   (M=8192,N=8192,K=2048)
    gemm256_kernel<true><<<dim3((2 * DI) / 256, BT_TOTAL / 256), 512, 0, stream>>>(
        (const ushort*)xb, (const ushort*)winb, xproj, BT_TOTAL, 2 * DI, DM);

    // 3) conv + silu + gate  (writes hbuf over dead xb/winb — stream-ordered)
    conv_silu_kernel<<<(BT_TOTAL * DI / 8) / 256, 256, 0, stream>>>(
        (const ushort*)xproj, cw, cb, Dv, (ushort*)hbuf);

    // 4) GEMM2: out[bt,c] = sum_d h[bt,d] * w_out[c,d]   (M=8192,N=2048,K=4096)
    gemm256_kernel<false><<<dim3(DM / 256, BT_TOTAL / 256), 512, 0, stream>>>(
        (const ushort*)hbuf, (const ushort*)woutb, out, BT_TOTAL, DM, DI);
}

// Round 5
// 613.409 us; speedup vs baseline: 1.6191x; 1.0549x over previous
//
#include <hip/hip_runtime.h>
#include <hip/hip_bf16.h>
#include <stdint.h>
#include <string.h>

// ---------------------------------------------------------------------------
// Mamba2 block: x@w_in^T -> split(xi,gate) -> depthwise causal conv4 + silu
//               -> *D*silu(gate) -> @w_out^T
// B=4, T=2048, D_MODEL=2048, D_INNER=4096.  GEMMs in bf16 MFMA, fp32 acc.
//
// R6: 256^2 / BK=64 / 8-wave / 8-phase, vmcnt(6) publishes at ph4/8. 50%.
// R7/R8: +32 VGPR frag double-buffer -> spill (WRITE 147->272 MB). Discarded.
// R9: single barrier per phase, R6 register set. 53% MfmaUtil, GEMM1 248us.
// R10: 2-D supertile XCD swizzle.  Staging demand is 2 GB/248us = 8.3 TB/s;
//     old 1-D chunking makes an XCD's 32 concurrent blocks one block-ROW:
//     1 shared A panel but 32 distinct B panels (32 MB) -> L2 (4 MiB/XCD)
//     thrash -> all B staging streams from L3/HBM -> VM6 stalls.  New
//     mapping: each XCD's concurrent 32 blocks form an 8(bm) x 4(bn)
//     rectangle: working set 8A+4B = 12 MB, B reused x8 / A x4 in L2;
//     past-L2 staging traffic ~2 GB -> ~384 MB.  Inner loop verbatim R9.
//     Bijective for both launches (1024 = 8 XCD x 4 st x 32; 256 = 8x1x32).
// ---------------------------------------------------------------------------

#define BT_TOTAL 8192   // B*T
#define DM 2048
#define DI 4096

typedef __attribute__((ext_vector_type(8)))  short short8;   // 8 x bf16
typedef __attribute__((ext_vector_type(16))) float f32x16;   // 32x32 C/D

__device__ __forceinline__ void async_ld16(const void* g, void* l) {
    __builtin_amdgcn_global_load_lds(
        (__attribute__((address_space(1))) void*)g,
        (__attribute__((address_space(3))) void*)l,
        16, 0, 0);
}

__device__ __forceinline__ float bf2f(ushort u) {
    union { uint i; float f; } v; v.i = ((uint)u) << 16; return v.f;
}

__device__ __forceinline__ ushort f2bf_bits(float f) {
    union { __hip_bfloat16 b; ushort u; } v;
    v.b = __float2bfloat16(f);
    return v.u;
}

// LDS regions (ushort indices), 128 KiB total: [A buf0][B buf0][A buf1][B buf1]
#define RA0 0
#define RB0 16384
#define RA1 32768
#define RB1 49152

#define BAR()   asm volatile("s_barrier" ::: "memory")
#define VM6()   asm volatile("s_waitcnt vmcnt(6)" ::: "memory")
#define VM0()   asm volatile("s_waitcnt vmcnt(0)" ::: "memory")
#define PRIO1() __builtin_amdgcn_s_setprio(1)
#define PRIO0() __builtin_amdgcn_s_setprio(0)

// gemm256: C[M,N] = A[M,K] * B[N,K]^T (both K-contiguous), bf16 in, fp32 acc.
// Requires M%256==0, N%256==0, K%128==0, K>=256, grid=(N/256, M/256),
// 512 thr, and (M/256)%8==0, (N/256)%4==0, nwg%256==0 for the supertile map.
template<bool OUT_BF16>
__global__ __launch_bounds__(512, 2) void gemm256_kernel(
    const ushort* __restrict__ A, const ushort* __restrict__ B,
    void* __restrict__ Cp, int M, int N, int K)
{
    __shared__ ushort lds[65536];   // 128 KiB

    const int tid  = threadIdx.x;
    const int lane = tid & 63;
    const int wave = tid >> 6;      // 8 waves: 2 (M) x 4 (N)
    const int wm   = wave >> 2;     // 0..1 -> 128 rows each
    const int wn   = wave & 3;      // 0..3 -> 64 cols each
    const int l31  = lane & 31;
    const int half = lane >> 5;

    // ---- 2-D supertile XCD swizzle (R10).  Supertile = 8 bm-rows x 4
    //      bn-cols = 32 blocks = one XCD's concurrent set.  Consecutive
    //      dispatch ids round-robin XCDs (orig&7); within an XCD, ids sweep
    //      u=0..31 (one supertile) before moving to its next supertile.
    const int nbx = gridDim.x;
    const int nwg = nbx * gridDim.y;
    const int orig = blockIdx.y * nbx + blockIdx.x;
    const int xcd  = orig & 7;
    const int t    = orig >> 3;              // [0, nwg/8)
    const int sloc = t >> 5;                 // supertile index within XCD
    const int u    = t & 31;                 // block within supertile
    const int spx  = (nwg >> 5) >> 3;        // supertiles per XCD
    const int g    = xcd * spx + sloc;       // global supertile id
    const int scols = nbx >> 2;              // supertile grid width (nbx/SN)
    const int sr   = g / scols;
    const int sc   = g - sr * scols;
    const int bm   = (sr * 8 + (u >> 2)) * 256;
    const int bn   = (sc * 4 + (u & 3)) * 256;

    // ---- staging precompute: thread tid covers 16B chunk (tid) of a
    //      64-row x 64-col quarter; source chunk pre-swizzled by f(row).
    const int rq = tid >> 3;                 // row within quarter
    const int jq = tid & 7;                  // chunk within row
    const int fq = (rq ^ (rq >> 3)) & 7;     // == f(qrow + rq) for qrow%64==0
    const int goffA = (bm + rq) * K + ((jq ^ fq) * 8);
    const int goffB = (bn + rq) * K + ((jq ^ fq) * 8);
    const int dst8  = tid * 8;               // linear LDS dest (ushorts)

    // ---- reader precompute (32x32x16 frags; logical chunk q = ks*2 + half,
    //      physical chunk = q ^ ((frag&1)*4) ^ flane)
    const int flane = (l31 ^ (l31 >> 3)) & 7;
    const int cl8   = (half ^ flane) * 8;            // chunk-xor base, x8 ush
    const int aBase = (wm * 128 + l31) * 64;         // within A region
    const int bBase = (wn * 64  + l31) * 64;         // within B region

    f32x16 acc[4][2];
#pragma unroll
    for (int m = 0; m < 4; ++m)
#pragma unroll
        for (int n = 0; n < 2; ++n)
#pragma unroll
            for (int r = 0; r < 16; ++r)
                acc[m][n][r] = 0.f;

    short8 aE[4], aO[4], b0[4], b1[4];   // R6 register set — no spill

#define STA(P, QROW, REG) async_ld16((P) + (size_t)(QROW) * K + goffA, \
                                     &lds[(REG) + (QROW) * 64 + dst8])
#define STB(P, QROW, REG) async_ld16((P) + (size_t)(QROW) * K + goffB, \
                                     &lds[(REG) + (QROW) * 64 + dst8])

#define RDA(MH, REG) do { \
    _Pragma("unroll") \
    for (int ks = 0; ks < 4; ++ks) { \
        aE[ks] = *(const short8*)&lds[(REG) + aBase + (MH)*4096 + (cl8 ^ (ks<<4))]; \
        aO[ks] = *(const short8*)&lds[(REG) + aBase + (MH)*4096 + 2048 + (cl8 ^ (ks<<4) ^ 32)]; \
    } } while (0)

#define RDB(DSTV, NF, REG) do { \
    _Pragma("unroll") \
    for (int ks = 0; ks < 4; ++ks) { \
        DSTV[ks] = *(const short8*)&lds[(REG) + bBase + (NF)*2048 + (cl8 ^ (ks<<4) ^ ((NF)<<5))]; \
    } } while (0)

#define MMA(MH, NH, BF) do { \
    _Pragma("unroll") \
    for (int ks = 0; ks < 4; ++ks) { \
        acc[(MH)*2    ][(NH)] = __builtin_amdgcn_mfma_f32_32x32x16_bf16( \
            aE[ks], BF[ks], acc[(MH)*2    ][(NH)], 0, 0, 0); \
        acc[(MH)*2 + 1][(NH)] = __builtin_amdgcn_mfma_f32_32x32x16_bf16( \
            aO[ks], BF[ks], acc[(MH)*2 + 1][(NH)], 0, 0, 0); \
    } } while (0)

    // ---- prologue: tile0 (8 quarters) + tile1 (6 quarters); the 7th/8th
    //      quarters of tile1 (B q1,q3) are staged in phase 1 of iter 0.
    {
        STA(A, 0, RA0);  STA(A, 128, RA0);
        STB(B, 0, RB0);  STB(B, 128, RB0);
        STA(A, 64, RA0); STA(A, 192, RA0);
        STB(B, 64, RB0); STB(B, 192, RB0);
        const ushort* Ap = A + 64;
        const ushort* Bp = B + 64;
        STA(Ap, 0, RA1);  STA(Ap, 128, RA1);
        STB(Bp, 0, RB1);  STB(Bp, 128, RB1);
        STA(Ap, 64, RA1); STA(Ap, 192, RA1);
        VM6(); BAR();   // tile0's 8 loads landed; tile1's 6 still in flight
    }

    const int NITER = K >> 7;   // 2 K-tiles (2x64) per iteration
    for (int i = 0; i < NITER; ++i) {
        const bool last = (i == NITER - 1);
        const int k1 = 128 * i + 64;    // K-tile 2i+1
        const int k2 = 128 * i + 128;   // K-tile 2i+2
        const int k3 = 128 * i + 192;   // K-tile 2i+3

        // phase 1: reads a(MH0)+b0 (buf0) | stage B(k1) q1,q3 -> buf1 | Q00
        RDA(0, RA0); RDB(b0, 0, RB0);
        STB(B + k1, 64, RB1); STB(B + k1, 192, RB1);
        PRIO1(); MMA(0, 0, b0); PRIO0();
        BAR();

        // phase 2: read b1 (buf0) | stage A(k2) q0,q2 -> buf0 | Q01
        RDB(b1, 1, RB0);
        if (!last) { STA(A + k2, 0, RA0); STA(A + k2, 128, RA0); }
        PRIO1(); MMA(0, 1, b1); PRIO0();
        BAR();

        // phase 3: read a(MH1) (buf0) | stage B(k2) q0,q2 -> buf0 | Q11
        RDA(1, RA0);
        if (!last) { STB(B + k2, 0, RB0); STB(B + k2, 128, RB0); }
        PRIO1(); MMA(1, 1, b1); PRIO0();
        BAR();

        // phase 4: stage A(k2) q1,q3 -> buf0 | Q10 | publish buf1 (tile 2i+1)
        if (!last) { STA(A + k2, 64, RA0); STA(A + k2, 192, RA0); }
        PRIO1(); MMA(1, 0, b0); PRIO0();
        if (last) { VM0(); } else { VM6(); }
        BAR();

        // phase 5: reads a(MH0)+b0 (buf1) | stage B(k2) q1,q3 -> buf0 | Q00
        RDA(0, RA1); RDB(b0, 0, RB1);
        if (!last) { STB(B + k2, 64, RB0); STB(B + k2, 192, RB0); }
        PRIO1(); MMA(0, 0, b0); PRIO0();
        BAR();

        // phase 6: read b1 (buf1) | stage A(k3) q0,q2 -> buf1 | Q01
        RDB(b1, 1, RB1);
        if (!last) { STA(A + k3, 0, RA1); STA(A + k3, 128, RA1); }
        PRIO1(); MMA(0, 1, b1); PRIO0();
        BAR();

        // phase 7: read a(MH1) (buf1) | stage B(k3) q0,q2 -> buf1 | Q11
        RDA(1, RA1);
        if (!last) { STB(B + k3, 0, RB1); STB(B + k3, 128, RB1); }
        PRIO1(); MMA(1, 1, b1); PRIO0();
        BAR();

        // phase 8: stage A(k3) q1,q3 -> buf1 | Q10 | publish buf0 (tile 2i+2)
        if (!last) { STA(A + k3, 64, RA1); STA(A + k3, 192, RA1); }
        PRIO1(); MMA(1, 0, b0); PRIO0();
        if (!last) { VM6(); BAR(); }
    }

    // ---- epilogue. 32x32 C/D layout (verified m74/m101):
    //   col = lane&31, row = (reg&3) + 8*(reg>>2) + 4*(lane>>5)
    const int col0 = bn + wn * 64 + l31;
    const int row0 = bm + wm * 128 + 4 * half;
    if (OUT_BF16) {
        __hip_bfloat16* C = (__hip_bfloat16*)Cp;
#pragma unroll
        for (int m = 0; m < 4; ++m)
#pragma unroll
            for (int n = 0; n < 2; ++n)
#pragma unroll
                for (int r = 0; r < 16; ++r) {
                    const int row = row0 + m * 32 + (r & 3) + 8 * (r >> 2);
                    C[(size_t)row * (size_t)N + col0 + n * 32] =
                        __float2bfloat16(acc[m][n][r]);
                }
    } else {
        float* C = (float*)Cp;
#pragma unroll
        for (int m = 0; m < 4; ++m)
#pragma unroll
            for (int n = 0; n < 2; ++n)
#pragma unroll
                for (int r = 0; r < 16; ++r) {
                    const int row = row0 + m * 32 + (r & 3) + 8 * (r >> 2);
                    C[(size_t)row * (size_t)N + col0 + n * 32] = acc[m][n][r];
                }
    }
}

// Depthwise causal conv (4 taps) + silu, * D, * silu(gate).  8 d's / thread.
__global__ __launch_bounds__(256) void conv_silu_kernel(
    const ushort* __restrict__ xp,   // bf16 [8192][8192]
    const float* __restrict__ cw,    // [4096][4]
    const float* __restrict__ cb,    // [4096]
    const float* __restrict__ Dv,    // [4096]
    ushort* __restrict__ h)          // bf16 [8192][4096]
{
    const int v  = blockIdx.x * 256 + threadIdx.x;   // over 8192*512
    const int d8 = (v & 511) * 8;
    const int bt = v >> 9;
    const int t  = bt & 2047;

    const uint4 gv = *(const uint4*)(xp + (size_t)bt * (2 * DI) + DI + d8);
    uint4 tap[4];
#pragma unroll
    for (int k = 0; k < 4; ++k) {
        const int tt = t - 3 + k;
        if (tt >= 0)
            tap[k] = *(const uint4*)(xp + (size_t)(bt - 3 + k) * (2 * DI) + d8);
        else
            tap[k] = (uint4){0u, 0u, 0u, 0u};
    }

    const float4* cwv = (const float4*)(cw + (size_t)d8 * 4);   // 8 x float4
    const float4  cb0 = *(const float4*)(cb + d8);
    const float4  cb1 = *(const float4*)(cb + d8 + 4);
    const float4  dv0 = *(const float4*)(Dv + d8);
    const float4  dv1 = *(const float4*)(Dv + d8 + 4);
    const float cbs[8] = {cb0.x, cb0.y, cb0.z, cb0.w, cb1.x, cb1.y, cb1.z, cb1.w};
    const float dvs[8] = {dv0.x, dv0.y, dv0.z, dv0.w, dv1.x, dv1.y, dv1.z, dv1.w};

    ushort res[8];
#pragma unroll
    for (int j = 0; j < 8; ++j) {
        float a = cbs[j];
        const float4 w = cwv[j];
        const float wk[4] = {w.x, w.y, w.z, w.w};
#pragma unroll
        for (int k = 0; k < 4; ++k) {
            const uint u = ((const uint*)&tap[k])[j >> 1];
            const ushort us = (j & 1) ? (ushort)(u >> 16) : (ushort)(u & 0xffff);
            a += bf2f(us) * wk[k];
        }
        const uint gu = ((const uint*)&gv)[j >> 1];
        const ushort gs = (j & 1) ? (ushort)(gu >> 16) : (ushort)(gu & 0xffff);
        const float g = bf2f(gs);
        const float sc = a / (1.f + __expf(-a));
        const float sg = g / (1.f + __expf(-g));
        res[j] = f2bf_bits(sc * dvs[j] * sg);
    }
    *(uint4*)(h + (size_t)bt * DI + d8) = *(const uint4*)res;
}

__global__ __launch_bounds__(256) void f32_to_bf16_x4(
    const float* __restrict__ in, __hip_bfloat16* __restrict__ out, int n4)
{
    const int i = blockIdx.x * 256 + threadIdx.x;
    if (i >= n4) return;
    const float4 v = *(const float4*)(in + (size_t)i * 4);
    union { __hip_bfloat16 hh[4]; ushort4 u; } cv;
    cv.hh[0] = __float2bfloat16(v.x);
    cv.hh[1] = __float2bfloat16(v.y);
    cv.hh[2] = __float2bfloat16(v.z);
    cv.hh[3] = __float2bfloat16(v.w);
    *(ushort4*)((ushort*)out + (size_t)i * 4) = cv.u;
}

extern "C" void kernel_launch(void* const* d_in, const int* in_sizes, int n_in,
                              void* d_out, int out_size, void* d_ws, size_t ws_size,
                              hipStream_t stream)
{
    const float* x     = (const float*)d_in[0];   // [4,2048,2048]
    const float* w_in  = (const float*)d_in[1];   // [8192,2048]
    const float* w_out = (const float*)d_in[2];   // [2048,4096]
    const float* cw    = (const float*)d_in[3];   // [4096,1,4]
    const float* cb    = (const float*)d_in[4];   // [4096]
    const float* Dv    = (const float*)d_in[5];   // [4096]
    float* out = (float*)d_out;                   // [4,2048,2048]

    // Workspace layout (208 MiB):
    //   [0, 128M)        x_proj bf16 [8192][8192]
    //   [128M, 192M)     phase 1: xb (32M) + winb (32M); phase 2: h bf16 (64M)
    //   [192M, 208M)     woutb [2048][4096] bf16
    char* wsc = (char*)d_ws;
    __hip_bfloat16* xproj = (__hip_bfloat16*)wsc;
    __hip_bfloat16* xb    = (__hip_bfloat16*)(wsc + (size_t)134217728);
    __hip_bfloat16* winb  = (__hip_bfloat16*)(wsc + (size_t)134217728 + 33554432);
    __hip_bfloat16* hbuf  = (__hip_bfloat16*)(wsc + (size_t)134217728);  // aliases xb/winb
    __hip_bfloat16* woutb = (__hip_bfloat16*)(wsc + (size_t)201326592);

    // 1) fp32 -> bf16 converts
    f32_to_bf16_x4<<<(BT_TOTAL * DM / 4 + 255) / 256, 256, 0, stream>>>(x, xb, BT_TOTAL * DM / 4);
    f32_to_bf16_x4<<<(2 * DI * DM / 4 + 255) / 256, 256, 0, stream>>>(w_in, winb, 2 * DI * DM / 4);
    f32_to_bf16_x4<<<(DM * DI / 4 + 255) / 256, 256, 0, stream>>>(w_out, woutb, DM * DI / 4);

    // 2) GEMM1: x_proj[bt,d] = sum_c x[bt,c] * w_in[d,c]   (M=8192,N=8192,K=2048)
    gemm256_kernel<true><<<dim3((2 * DI) / 256, BT_TOTAL / 256), 512, 0, stream>>>(
        (const ushort*)xb, (const ushort*)winb, xproj, BT_TOTAL, 2 * DI, DM);

    // 3) conv + silu + gate  (writes hbuf over dead xb/winb — stream-ordered)
    conv_silu_kernel<<<(BT_TOTAL * DI / 8) / 256, 256, 0, stream>>>(
        (const ushort*)xproj, cw, cb, Dv, (ushort*)hbuf);

    // 4) GEMM2: out[bt,c] = sum_d h[bt,d] * w_out[c,d]   (M=8192,N=2048,K=4096)
    gemm256_kernel<false><<<dim3(DM / 256, BT_TOTAL / 256), 512, 0, stream>>>(
        (const ushort*)hbuf, (const ushort*)woutb, out, BT_TOTAL, DM, DI);
}